// Round 6
// baseline (696.446 us; speedup 1.0000x reference)
//
#include <hip/hip_runtime.h>

#define N_NODES 100000
#define N_PAIRS 1600000
#define EDGE_NUM 30000
#define D 64
#define NEG_SLOPE 0.2f
#define NG 128  // pair-chunks for the XCD-pinned fill (grid = 8*NG)

// ---------------------------------------------------------------------------
// CSR build: fused histograms (nt loads) -> 2-block scan -> XCD-pinned fill
// ---------------------------------------------------------------------------
__global__ __launch_bounds__(256) void hist2_kernel(
    const int* __restrict__ edges, const int* __restrict__ vertex,
    int* __restrict__ ecnt, int* __restrict__ vcnt, int n)
{
    const int i = blockIdx.x * blockDim.x + threadIdx.x;
    if (i < n) {
        const int e = __builtin_nontemporal_load(&edges[i]);
        const int v = __builtin_nontemporal_load(&vertex[i]);
        atomicAdd(&ecnt[e], 1);
        atomicAdd(&vcnt[v], 1);
    }
}

// 16 elements per thread per chunk (16384/chunk with 1024 threads)
__device__ void scan_body(const int* cnt, int* off, int* cur, int n)
{
    __shared__ int wsum[16];
    __shared__ int s_carry;
    if (threadIdx.x == 0) s_carry = 0;
    __syncthreads();
    const int lane = threadIdx.x & 63;
    const int wave = threadIdx.x >> 6;

    for (int base = 0; base < n; base += 16384) {
        const int i0 = base + threadIdx.x * 16;
        int x[16];
        #pragma unroll
        for (int q = 0; q < 4; ++q) {
            const int ii = i0 + q * 4;
            if (ii + 3 < n) {
                int4 t = *(const int4*)&cnt[ii];
                x[q*4] = t.x; x[q*4+1] = t.y; x[q*4+2] = t.z; x[q*4+3] = t.w;
            } else {
                #pragma unroll
                for (int r = 0; r < 4; ++r) x[q*4+r] = (ii + r < n) ? cnt[ii + r] : 0;
            }
        }
        int tsum = 0;
        #pragma unroll
        for (int q = 0; q < 16; ++q) tsum += x[q];
        int sc = tsum;
        #pragma unroll
        for (int s = 1; s < 64; s <<= 1) {
            int y = __shfl_up(sc, s);
            if (lane >= s) sc += y;
        }
        if (lane == 63) wsum[wave] = sc;
        __syncthreads();
        int wbase = 0;
        for (int w = 0; w < wave; ++w) wbase += wsum[w];
        const int carry = s_carry;
        int run = carry + wbase + sc - tsum;   // exclusive prefix for this thread
        int y[16];
        #pragma unroll
        for (int q = 0; q < 16; ++q) { y[q] = run; run += x[q]; }
        #pragma unroll
        for (int q = 0; q < 4; ++q) {
            const int ii = i0 + q * 4;
            if (ii + 3 < n) {
                *(int4*)&off[ii] = make_int4(y[q*4], y[q*4+1], y[q*4+2], y[q*4+3]);
                *(int4*)&cur[ii] = make_int4(y[q*4], y[q*4+1], y[q*4+2], y[q*4+3]);
            } else {
                #pragma unroll
                for (int r = 0; r < 4; ++r)
                    if (ii + r < n) { off[ii+r] = y[q*4+r]; cur[ii+r] = y[q*4+r]; }
            }
        }
        __syncthreads();
        if (threadIdx.x == 1023) s_carry = carry + wbase + sc;  // chunk total
        __syncthreads();
    }
    if (threadIdx.x == 0) off[n] = s_carry;
}

__global__ __launch_bounds__(1024) void scan2_kernel(
    int* ecnt, int* eoff, int* vcnt, int* voff)
{
    if (blockIdx.x == 0) scan_body(ecnt, eoff, ecnt, EDGE_NUM);
    else                 scan_body(vcnt, voff, vcnt, N_NODES);
}

// XCD-pinned fill (blockIdx%8 -> XCD). nt loads keep the 12.8 MB pair-list
// stream from evicting the ~1.6 MB/XCD CSR write set out of L2.
__global__ __launch_bounds__(256) void fill_xcd_kernel(
    const int* __restrict__ edges, const int* __restrict__ vertex,
    int* __restrict__ ecur, int* __restrict__ vcur,
    int* __restrict__ evlist, int* __restrict__ velist)
{
    const int xcd = blockIdx.x & 7;
    const int grp = blockIdx.x >> 3;
    const int elo = xcd * (EDGE_NUM / 8);
    const int ehi = elo + (EDGE_NUM / 8);
    const int vlo = xcd * (N_NODES / 8);
    const int vhi = vlo + (N_NODES / 8);

    for (int i = grp * 256 + threadIdx.x; i < N_PAIRS; i += NG * 256) {
        const int e = __builtin_nontemporal_load(&edges[i]);
        const int v = __builtin_nontemporal_load(&vertex[i]);
        if (e >= elo && e < ehi) evlist[atomicAdd(&ecur[e], 1)] = v;
        if (v >= vlo && v < vhi) velist[atomicAdd(&vcur[v], 1)] = e;
    }
}

// ---------------------------------------------------------------------------
// Per-edge gather. One wave per edge. Masked 16-wide batches: 16 independent
// X-row loads in flight, zero-weight FMA for tail -> no serial remainder.
// ---------------------------------------------------------------------------
__global__ __launch_bounds__(256) void edge_gather_kernel(
    const float* __restrict__ X, const float* __restrict__ degV,
    const float* __restrict__ Ww, const float* __restrict__ Wb,
    const int* __restrict__ eoff, const int* __restrict__ evlist,
    float* __restrict__ Xe)
{
    const int lane = threadIdx.x & 63;
    const int wave = threadIdx.x >> 6;
    const int e = blockIdx.x * 4 + wave;
    const int t = (e >= 10000) + (e >= 20000);   // uniform per block (bounds %4==0)

    float w[64];
    const float* wrow = Ww + ((size_t)(t + 1) * 64 + lane) * 64;
    #pragma unroll
    for (int i = 0; i < 64; i += 4) {
        float4 v = *(const float4*)(wrow + i);
        w[i] = v.x; w[i+1] = v.y; w[i+2] = v.z; w[i+3] = v.w;
    }
    const float b = Wb[(t + 1) * 64 + lane];

    const int start = eoff[e], end = eoff[e + 1];
    const float* __restrict__ degt = degV + (size_t)t * N_NODES;
    const float* __restrict__ Xl = X + lane;

    float acc0 = 0.f, acc1 = 0.f, acc2 = 0.f, acc3 = 0.f, sdeg = 0.f;
    for (int j0 = start; j0 < end; j0 += 64) {
        const int m = min(64, end - j0);
        const int vv = (lane < m) ? __builtin_nontemporal_load(&evlist[j0 + lane]) : 0;
        for (int j = 0; j < m; j += 16) {
            int v[16]; float s[16], f[16];
            #pragma unroll
            for (int u = 0; u < 16; ++u) v[u] = __shfl(vv, j + u);  // invalid lanes hold 0
            #pragma unroll
            for (int u = 0; u < 16; ++u) f[u] = Xl[(size_t)v[u] * D];
            #pragma unroll
            for (int u = 0; u < 16; ++u) s[u] = (j + u < m) ? degt[v[u]] : 0.f;
            #pragma unroll
            for (int u = 0; u < 16; u += 4) {
                acc0 = fmaf(s[u],     f[u],     acc0);
                acc1 = fmaf(s[u + 1], f[u + 1], acc1);
                acc2 = fmaf(s[u + 2], f[u + 2], acc2);
                acc3 = fmaf(s[u + 3], f[u + 3], acc3);
                sdeg += (s[u] + s[u + 1]) + (s[u + 2] + s[u + 3]);
            }
        }
    }
    const float acc = (acc0 + acc1) + (acc2 + acc3);

    float r = 0.f;
    #pragma unroll
    for (int i = 0; i < 64; ++i) r = fmaf(__shfl(acc, i), w[i], r);
    r += sdeg * b;
    const int k = max(end - start, 1);
    Xe[(size_t)e * D + lane] = r / (float)k;
}

// ---------------------------------------------------------------------------
// Per-vertex: fused X0 matvec (on-the-fly) + edge gather + L2 norm + leaky.
// ---------------------------------------------------------------------------
__global__ __launch_bounds__(256) void vertex_gather_kernel(
    const float* __restrict__ X, const float* __restrict__ Ww,
    const float* __restrict__ Wb, const float* __restrict__ Xe,
    const int* __restrict__ voff, const int* __restrict__ velist,
    float* __restrict__ out)
{
    const int v = blockIdx.x * 4 + (threadIdx.x >> 6);
    const int lane = threadIdx.x & 63;

    float w[64];                       // W0 row for output channel `lane`
    const float* wrow = Ww + (size_t)lane * 64;
    #pragma unroll
    for (int i = 0; i < 64; i += 4) {
        float4 t = *(const float4*)(wrow + i);
        w[i] = t.x; w[i+1] = t.y; w[i+2] = t.z; w[i+3] = t.w;
    }
    const float b = Wb[lane];

    // X0[v][lane] = sum_i X[v][i]*W0[lane][i] + b  (same FMA order as before)
    const float xr = X[(size_t)v * D + lane];
    float x0 = 0.f;
    #pragma unroll
    for (int i = 0; i < 64; ++i) x0 = fmaf(__shfl(xr, i), w[i], x0);

    const int start = voff[v], end = voff[v + 1];
    const float* __restrict__ Xel = Xe + lane;

    float acc0 = x0 + b, acc1 = 0.f, acc2 = 0.f, acc3 = 0.f;
    for (int j0 = start; j0 < end; j0 += 64) {
        const int m = min(64, end - j0);
        const int ee = (lane < m) ? __builtin_nontemporal_load(&velist[j0 + lane]) : 0;
        for (int j = 0; j < m; j += 16) {
            int e[16]; float f[16], msk[16];
            #pragma unroll
            for (int u = 0; u < 16; ++u) e[u] = __shfl(ee, j + u);
            #pragma unroll
            for (int u = 0; u < 16; ++u) f[u] = Xel[(size_t)e[u] * D];
            #pragma unroll
            for (int u = 0; u < 16; ++u) msk[u] = (j + u < m) ? 1.f : 0.f;
            #pragma unroll
            for (int u = 0; u < 16; u += 4) {
                acc0 = fmaf(msk[u],     f[u],     acc0);
                acc1 = fmaf(msk[u + 1], f[u + 1], acc1);
                acc2 = fmaf(msk[u + 2], f[u + 2], acc2);
                acc3 = fmaf(msk[u + 3], f[u + 3], acc3);
            }
        }
    }
    const float acc = (acc0 + acc1) + (acc2 + acc3);

    float ss = acc * acc;
    #pragma unroll
    for (int off = 1; off < 64; off <<= 1) ss += __shfl_xor(ss, off);
    const float rn = sqrtf(ss);
    const float scale = (rn == 0.f) ? 0.f : 1.f / rn;
    const float y = acc * scale;
    out[(size_t)v * D + lane] = (y > 0.f) ? y : NEG_SLOPE * y;
}

// ---------------------------------------------------------------------------
extern "C" void kernel_launch(void* const* d_in, const int* in_sizes, int n_in,
                              void* d_out, int out_size, void* d_ws, size_t ws_size,
                              hipStream_t stream)
{
    const float* X      = (const float*)d_in[0];   // (100000, 64)
    const float* degV   = (const float*)d_in[1];   // (3, 100000, 1)
    const float* Ww     = (const float*)d_in[2];   // (4, 64, 64)
    const float* Wb     = (const float*)d_in[3];   // (4, 64)
    const int*   vertex = (const int*)d_in[4];     // (1600000,)
    const int*   edges  = (const int*)d_in[5];     // (1600000,)
    float* out = (float*)d_out;                    // (100000, 64)

    // workspace layout (~21.5 MB)
    float* Xe    = (float*)d_ws;              // 1,920,000 f32 (7.68 MB)
    int*   ib    = (int*)(Xe + 1920000);
    int* eoff    = ib;                        // 30001 (pad to 30004)
    int* ecur    = ib + 30004;                // 30000 (pad to 30004)
    int* voff    = ib + 60008;                // 100001 (pad to 100004)
    int* vcur    = ib + 160012;               // 100000
    int* evlist  = ib + 260012;               // 1,600,000
    int* velist  = ib + 1860012;              // 1,600,000

    hipMemsetAsync(ib, 0, (size_t)260012 * sizeof(int), stream);

    const int pb = (N_PAIRS + 255) / 256;     // 6250
    hist2_kernel<<<pb, 256, 0, stream>>>(edges, vertex, ecur, vcur, N_PAIRS);
    scan2_kernel<<<2, 1024, 0, stream>>>(ecur, eoff, vcur, voff);
    fill_xcd_kernel<<<8 * NG, 256, 0, stream>>>(edges, vertex, ecur, vcur,
                                                evlist, velist);

    edge_gather_kernel<<<EDGE_NUM / 4, 256, 0, stream>>>(
        X, degV, Ww, Wb, eoff, evlist, Xe);

    vertex_gather_kernel<<<N_NODES / 4, 256, 0, stream>>>(
        X, Ww, Wb, Xe, voff, velist, out);
}

// Round 7
// 660.554 us; speedup vs baseline: 1.0543x; 1.0543x over previous
//
#include <hip/hip_runtime.h>

#define N_NODES 100000
#define N_PAIRS 1600000
#define EDGE_NUM 30000
#define D 64
#define NEG_SLOPE 0.2f
#define NG 128  // pair-chunks for the XCD-pinned fill (grid = 8*NG)

// ---------------------------------------------------------------------------
// CSR build: fused histograms -> 2-block scan -> XCD-pinned fill
// (NO nontemporal loads anywhere: R6 showed nt defeats LLC reuse on gfx950.)
// ---------------------------------------------------------------------------
__global__ __launch_bounds__(256) void hist2_kernel(
    const int* __restrict__ edges, const int* __restrict__ vertex,
    int* __restrict__ ecnt, int* __restrict__ vcnt, int n)
{
    const int i = blockIdx.x * blockDim.x + threadIdx.x;
    if (i < n) {
        atomicAdd(&ecnt[edges[i]], 1);
        atomicAdd(&vcnt[vertex[i]], 1);
    }
}

// 16 elements per thread per chunk (16384/chunk with 1024 threads)
__device__ void scan_body(const int* cnt, int* off, int* cur, int n)
{
    __shared__ int wsum[16];
    __shared__ int s_carry;
    if (threadIdx.x == 0) s_carry = 0;
    __syncthreads();
    const int lane = threadIdx.x & 63;
    const int wave = threadIdx.x >> 6;

    for (int base = 0; base < n; base += 16384) {
        const int i0 = base + threadIdx.x * 16;
        int x[16];
        #pragma unroll
        for (int q = 0; q < 4; ++q) {
            const int ii = i0 + q * 4;
            if (ii + 3 < n) {
                int4 t = *(const int4*)&cnt[ii];
                x[q*4] = t.x; x[q*4+1] = t.y; x[q*4+2] = t.z; x[q*4+3] = t.w;
            } else {
                #pragma unroll
                for (int r = 0; r < 4; ++r) x[q*4+r] = (ii + r < n) ? cnt[ii + r] : 0;
            }
        }
        int tsum = 0;
        #pragma unroll
        for (int q = 0; q < 16; ++q) tsum += x[q];
        int sc = tsum;
        #pragma unroll
        for (int s = 1; s < 64; s <<= 1) {
            int y = __shfl_up(sc, s);
            if (lane >= s) sc += y;
        }
        if (lane == 63) wsum[wave] = sc;
        __syncthreads();
        int wbase = 0;
        for (int w = 0; w < wave; ++w) wbase += wsum[w];
        const int carry = s_carry;
        int run = carry + wbase + sc - tsum;
        int y[16];
        #pragma unroll
        for (int q = 0; q < 16; ++q) { y[q] = run; run += x[q]; }
        #pragma unroll
        for (int q = 0; q < 4; ++q) {
            const int ii = i0 + q * 4;
            if (ii + 3 < n) {
                *(int4*)&off[ii] = make_int4(y[q*4], y[q*4+1], y[q*4+2], y[q*4+3]);
                *(int4*)&cur[ii] = make_int4(y[q*4], y[q*4+1], y[q*4+2], y[q*4+3]);
            } else {
                #pragma unroll
                for (int r = 0; r < 4; ++r)
                    if (ii + r < n) { off[ii+r] = y[q*4+r]; cur[ii+r] = y[q*4+r]; }
            }
        }
        __syncthreads();
        if (threadIdx.x == 1023) s_carry = carry + wbase + sc;
        __syncthreads();
    }
    if (threadIdx.x == 0) off[n] = s_carry;
}

__global__ __launch_bounds__(1024) void scan2_kernel(
    int* ecnt, int* eoff, int* vcnt, int* voff)
{
    if (blockIdx.x == 0) scan_body(ecnt, eoff, ecnt, EDGE_NUM);
    else                 scan_body(vcnt, voff, vcnt, N_NODES);
}

// XCD-pinned fill (blockIdx%8 -> XCD): each XCD owns one key range, so its
// ~1.6 MB CSR write set stays in its own L2 (R5: 198->153 MB WRITE_SIZE).
__global__ __launch_bounds__(256) void fill_xcd_kernel(
    const int* __restrict__ edges, const int* __restrict__ vertex,
    int* __restrict__ ecur, int* __restrict__ vcur,
    int* __restrict__ evlist, int* __restrict__ velist)
{
    const int xcd = blockIdx.x & 7;
    const int grp = blockIdx.x >> 3;
    const int elo = xcd * (EDGE_NUM / 8);
    const int ehi = elo + (EDGE_NUM / 8);
    const int vlo = xcd * (N_NODES / 8);
    const int vhi = vlo + (N_NODES / 8);

    for (int i = grp * 256 + threadIdx.x; i < N_PAIRS; i += NG * 256) {
        const int e = edges[i];
        const int v = vertex[i];
        if (e >= elo && e < ehi) evlist[atomicAdd(&ecur[e], 1)] = v;
        if (v >= vlo && v < vhi) velist[atomicAdd(&vcur[v], 1)] = e;
    }
}

// ---------------------------------------------------------------------------
// Per-edge gather. One wave per edge. Software-pipelined 8-batches (16 loads
// in flight steady-state via fine-grained vmcnt) + masked-8 tail (no serial
// remainder).
// ---------------------------------------------------------------------------
__global__ __launch_bounds__(256) void edge_gather_kernel(
    const float* __restrict__ X, const float* __restrict__ degV,
    const float* __restrict__ Ww, const float* __restrict__ Wb,
    const int* __restrict__ eoff, const int* __restrict__ evlist,
    float* __restrict__ Xe)
{
    const int lane = threadIdx.x & 63;
    const int wave = threadIdx.x >> 6;
    const int e = blockIdx.x * 4 + wave;
    const int t = (e >= 10000) + (e >= 20000);   // uniform per block (bounds %4==0)

    const int start = eoff[e], end = eoff[e + 1];
    const float* __restrict__ degt = degV + (size_t)t * N_NODES;
    const float* __restrict__ Xl = X + lane;

    float acc0 = 0.f, acc1 = 0.f, sdeg = 0.f;
    for (int j0 = start; j0 < end; j0 += 64) {
        const int m = min(64, end - j0);
        const int vv = (lane < m) ? evlist[j0 + lane] : 0;
        const int nb = (m + 7) >> 3;
        int vc[8]; float fc[8], sc[8];
        #pragma unroll
        for (int u = 0; u < 8; ++u) vc[u] = __shfl(vv, u);
        #pragma unroll
        for (int u = 0; u < 8; ++u) fc[u] = Xl[(size_t)vc[u] * D];
        #pragma unroll
        for (int u = 0; u < 8; ++u) sc[u] = (u < m) ? degt[vc[u]] : 0.f;
        for (int bi = 0; bi < nb; ++bi) {
            const int jn = bi * 8 + 8;
            const bool more = (bi + 1 < nb);
            int vn[8]; float fn[8], sn[8];
            if (more) {
                #pragma unroll
                for (int u = 0; u < 8; ++u) vn[u] = __shfl(vv, jn + u);
                #pragma unroll
                for (int u = 0; u < 8; ++u) fn[u] = Xl[(size_t)vn[u] * D];
                #pragma unroll
                for (int u = 0; u < 8; ++u) sn[u] = (jn + u < m) ? degt[vn[u]] : 0.f;
            }
            #pragma unroll
            for (int u = 0; u < 8; u += 2) {
                acc0 = fmaf(sc[u],     fc[u],     acc0);
                acc1 = fmaf(sc[u + 1], fc[u + 1], acc1);
                sdeg += sc[u] + sc[u + 1];
            }
            if (more) {
                #pragma unroll
                for (int u = 0; u < 8; ++u) { vc[u]=vn[u]; fc[u]=fn[u]; sc[u]=sn[u]; }
            }
        }
    }
    const float acc = acc0 + acc1;

    // epilogue: r[lane] = sum_i acc_i * W[t+1][lane][i] + sdeg*b; /= k
    float w[64];
    const float* wrow = Ww + ((size_t)(t + 1) * 64 + lane) * 64;
    #pragma unroll
    for (int i = 0; i < 64; i += 4) {
        float4 v = *(const float4*)(wrow + i);
        w[i] = v.x; w[i+1] = v.y; w[i+2] = v.z; w[i+3] = v.w;
    }
    float r = 0.f;
    #pragma unroll
    for (int i = 0; i < 64; ++i) r = fmaf(__shfl(acc, i), w[i], r);
    r += sdeg * Wb[(t + 1) * 64 + lane];
    const int k = max(end - start, 1);
    Xe[(size_t)e * D + lane] = r / (float)k;
}

// ---------------------------------------------------------------------------
// Per-vertex: pipelined edge gather + fused X0 matvec (epilogue) + L2 norm
// + leaky relu.
// ---------------------------------------------------------------------------
__global__ __launch_bounds__(256) void vertex_gather_kernel(
    const float* __restrict__ X, const float* __restrict__ Ww,
    const float* __restrict__ Wb, const float* __restrict__ Xe,
    const int* __restrict__ voff, const int* __restrict__ velist,
    float* __restrict__ out)
{
    const int v = blockIdx.x * 4 + (threadIdx.x >> 6);
    const int lane = threadIdx.x & 63;
    const int start = voff[v], end = voff[v + 1];
    const float* __restrict__ Xel = Xe + lane;

    float acc0 = 0.f, acc1 = 0.f;
    for (int j0 = start; j0 < end; j0 += 64) {
        const int m = min(64, end - j0);
        const int ee = (lane < m) ? velist[j0 + lane] : 0;
        const int nb = (m + 7) >> 3;
        int ec[8]; float fc[8], mc[8];
        #pragma unroll
        for (int u = 0; u < 8; ++u) ec[u] = __shfl(ee, u);
        #pragma unroll
        for (int u = 0; u < 8; ++u) fc[u] = Xel[(size_t)ec[u] * D];
        #pragma unroll
        for (int u = 0; u < 8; ++u) mc[u] = (u < m) ? 1.f : 0.f;
        for (int bi = 0; bi < nb; ++bi) {
            const int jn = bi * 8 + 8;
            const bool more = (bi + 1 < nb);
            int en[8]; float fn[8], mn[8];
            if (more) {
                #pragma unroll
                for (int u = 0; u < 8; ++u) en[u] = __shfl(ee, jn + u);
                #pragma unroll
                for (int u = 0; u < 8; ++u) fn[u] = Xel[(size_t)en[u] * D];
                #pragma unroll
                for (int u = 0; u < 8; ++u) mn[u] = (jn + u < m) ? 1.f : 0.f;
            }
            #pragma unroll
            for (int u = 0; u < 8; u += 2) {
                acc0 = fmaf(mc[u],     fc[u],     acc0);
                acc1 = fmaf(mc[u + 1], fc[u + 1], acc1);
            }
            if (more) {
                #pragma unroll
                for (int u = 0; u < 8; ++u) { ec[u]=en[u]; fc[u]=fn[u]; mc[u]=mn[u]; }
            }
        }
    }

    // epilogue: X0[v][lane] = sum_i X[v][i]*W0[lane][i] + b
    float w[64];
    const float* wrow = Ww + (size_t)lane * 64;
    #pragma unroll
    for (int i = 0; i < 64; i += 4) {
        float4 t4 = *(const float4*)(wrow + i);
        w[i] = t4.x; w[i+1] = t4.y; w[i+2] = t4.z; w[i+3] = t4.w;
    }
    const float xr = X[(size_t)v * D + lane];
    float x0 = 0.f;
    #pragma unroll
    for (int i = 0; i < 64; ++i) x0 = fmaf(__shfl(xr, i), w[i], x0);

    const float acc = (acc0 + acc1) + (x0 + Wb[lane]);

    float ss = acc * acc;
    #pragma unroll
    for (int off = 1; off < 64; off <<= 1) ss += __shfl_xor(ss, off);
    const float rn = sqrtf(ss);
    const float scale = (rn == 0.f) ? 0.f : 1.f / rn;
    const float y = acc * scale;
    out[(size_t)v * D + lane] = (y > 0.f) ? y : NEG_SLOPE * y;
}

// ---------------------------------------------------------------------------
extern "C" void kernel_launch(void* const* d_in, const int* in_sizes, int n_in,
                              void* d_out, int out_size, void* d_ws, size_t ws_size,
                              hipStream_t stream)
{
    const float* X      = (const float*)d_in[0];   // (100000, 64)
    const float* degV   = (const float*)d_in[1];   // (3, 100000, 1)
    const float* Ww     = (const float*)d_in[2];   // (4, 64, 64)
    const float* Wb     = (const float*)d_in[3];   // (4, 64)
    const int*   vertex = (const int*)d_in[4];     // (1600000,)
    const int*   edges  = (const int*)d_in[5];     // (1600000,)
    float* out = (float*)d_out;                    // (100000, 64)

    // workspace layout (~21.5 MB)
    float* Xe    = (float*)d_ws;              // 1,920,000 f32 (7.68 MB)
    int*   ib    = (int*)(Xe + 1920000);
    int* eoff    = ib;                        // 30001 (pad to 30004)
    int* ecur    = ib + 30004;                // 30000 (pad to 30004)
    int* voff    = ib + 60008;                // 100001 (pad to 100004)
    int* vcur    = ib + 160012;               // 100000
    int* evlist  = ib + 260012;               // 1,600,000
    int* velist  = ib + 1860012;              // 1,600,000

    hipMemsetAsync(ib, 0, (size_t)260012 * sizeof(int), stream);

    const int pb = (N_PAIRS + 255) / 256;     // 6250
    hist2_kernel<<<pb, 256, 0, stream>>>(edges, vertex, ecur, vcur, N_PAIRS);
    scan2_kernel<<<2, 1024, 0, stream>>>(ecur, eoff, vcur, voff);
    fill_xcd_kernel<<<8 * NG, 256, 0, stream>>>(edges, vertex, ecur, vcur,
                                                evlist, velist);

    edge_gather_kernel<<<EDGE_NUM / 4, 256, 0, stream>>>(
        X, degV, Ww, Wb, eoff, evlist, Xe);

    vertex_gather_kernel<<<N_NODES / 4, 256, 0, stream>>>(
        X, Ww, Wb, Xe, voff, velist, out);
}